// Round 2
// baseline (103.635 us; speedup 1.0000x reference)
//
#include <hip/hip_runtime.h>

// Problem shape (fixed by the harness / reference setup_inputs)
constexpr int B = 8;
constexpr int A = 49104;
constexpr int C = 90;     // classes
constexpr int M = 32;     // max GT boxes
constexpr float EPS_CLIP = 1e-4f;
constexpr float LN2 = 0.6931471805599453f;

constexpr int APB = 128;  // anchors per block
constexpr int TPB = 256;  // threads per block

// d_ws accumulator layout (floats): [0..B) cls_sum(raw, scale by -ln2), [B..2B) reg_sum, [2B..3B) pos_cnt

__global__ __launch_bounds__(TPB) void focal_fused_kernel(
    const float* __restrict__ cls,   // [B, A, C]
    const float* __restrict__ reg,   // [B, A, 4]
    const float* __restrict__ anc,   // [A, 4]
    const float* __restrict__ ann,   // [B, M, 5]
    float* __restrict__ accum)       // [3*B]
{
    __shared__ float s_ann[M * 5];
    __shared__ int   s_meta[APB + 1];       // class idx if pos, -1 neg, -2 ignore
    __shared__ float s_red[3][TPB / 64];

    const int b     = blockIdx.y;
    const int abase = blockIdx.x * APB;
    const int t     = threadIdx.x;
    const int nA    = min(APB, A - abase);  // anchors this block handles (even)

    if (t < M * 5) s_ann[t] = ann[b * M * 5 + t];
    __syncthreads();

    float reg_sum = 0.f;
    float pos_cnt = 0.f;
    int   mymeta  = -1;

    // ---------- Phase 1: per-anchor GT assignment + regression loss ----------
    if (t < nA) {
        const int a = abase + t;
        const float4 ab = reinterpret_cast<const float4*>(anc)[a];
        const float aw = ab.z - ab.x;
        const float ah = ab.w - ab.y;
        const float areaA = aw * ah;

        float best = -INFINITY;
        int argm = 0;
        for (int m = 0; m < M; ++m) {
            const float bx1 = s_ann[m * 5 + 0];
            const float by1 = s_ann[m * 5 + 1];
            const float bx2 = s_ann[m * 5 + 2];
            const float by2 = s_ann[m * 5 + 3];
            const float lab = s_ann[m * 5 + 4];
            float iw = fminf(ab.z, bx2) - fmaxf(ab.x, bx1);
            float ih = fminf(ab.w, by2) - fmaxf(ab.y, by1);
            iw = fmaxf(iw, 0.f);
            ih = fmaxf(ih, 0.f);
            const float inter = iw * ih;
            const float ua = fmaxf(areaA + (bx2 - bx1) * (by2 - by1) - inter, 1e-8f);
            const float iou = inter / ua;
            const float val = (lab != -1.0f) ? iou : -1.0f;
            if (val > best) { best = val; argm = m; }  // strict > == first argmax
        }

        const bool pos = best >= 0.5f;
        const bool neg = best < 0.4f;
        mymeta = pos ? (int)s_ann[argm * 5 + 4] : (neg ? -1 : -2);

        if (pos) {
            pos_cnt = 1.f;
            const float gx1 = s_ann[argm * 5 + 0];
            const float gy1 = s_ann[argm * 5 + 1];
            const float gx2 = s_ann[argm * 5 + 2];
            const float gy2 = s_ann[argm * 5 + 3];
            const float acx = ab.x + 0.5f * aw;
            const float acy = ab.y + 0.5f * ah;
            const float gw0 = gx2 - gx1;
            const float gh0 = gy2 - gy1;
            const float gcx = gx1 + 0.5f * gw0;
            const float gcy = gy1 + 0.5f * gh0;
            const float gw = fmaxf(gw0, 1.f);
            const float gh = fmaxf(gh0, 1.f);
            const float4 rp = reinterpret_cast<const float4*>(reg)[(size_t)b * A + a];
            const float rt0 = (gcx - acx) / aw * 10.f;
            const float rt1 = (gcy - acy) / ah * 10.f;
            const float rt2 = __logf(gw / aw) * 5.f;
            const float rt3 = __logf(gh / ah) * 5.f;
            const float d0 = fabsf(rt0 - rp.x);
            const float d1 = fabsf(rt1 - rp.y);
            const float d2 = fabsf(rt2 - rp.z);
            const float d3 = fabsf(rt3 - rp.w);
            auto sl1 = [](float d) {
                return (d <= (1.f / 9.f)) ? 4.5f * d * d : d - (0.5f / 9.f);
            };
            reg_sum = sl1(d0) + sl1(d1) + sl1(d2) + sl1(d3);
        }
    }
    if (t < APB + 1) s_meta[t] = (t < nA) ? 0 : -1;   // placeholder; rewritten below
    if (t < nA) s_meta[t] = mymeta;
    const int nspecial = __syncthreads_count(mymeta != -1);  // barrier + count

    // ---------- Phase 2: stream classifications, focal loss ----------
    // acc accumulates  sum( w/alpha-folded * log2(parg) )  (negative); final scale -ln2.
    float acc = 0.f;
    const float4* cp = reinterpret_cast<const float4*>(
        cls + ((size_t)b * A + abase) * (size_t)C);
    const int n4 = (nA * C) >> 2;  // exact: nA even -> nA*90 % 4 == 0

    if (nspecial == 0) {
        // FAST: every anchor in this block is a plain negative (target 0 everywhere).
        // loss_elem = 0.75 * p^2 * (-log(1-p)) = -0.75*ln2 * ( p^2 * log2(1-p) )
        auto body = [&](float4 v) {
            const float vv[4] = {v.x, v.y, v.z, v.w};
#pragma unroll
            for (int j = 0; j < 4; ++j) {
                const float p = fminf(fmaxf(vv[j], EPS_CLIP), 1.f - EPS_CLIP);
                const float q = 1.f - p;
                acc = fmaf(0.75f * p * p, __log2f(q), acc);
            }
        };
        int i = t;
        for (; i + TPB < n4; i += 2 * TPB) {   // 2-deep MLP
            const float4 va = cp[i];
            const float4 vb = cp[i + TPB];
            body(va);
            body(vb);
        }
        if (i < n4) body(cp[i]);
    } else {
        // SLOW: block contains positive / ignore anchors.
        for (int i = t; i < n4; i += TPB) {
            const float4 v = cp[i];
            const int e  = i << 2;
            const int a0 = e / C;
            const int c0 = e - a0 * C;
            const int m0 = s_meta[a0];
            const int m1 = (c0 >= C - 3) ? s_meta[a0 + 1] : m0;
            const float vv[4] = {v.x, v.y, v.z, v.w};
#pragma unroll
            for (int j = 0; j < 4; ++j) {
                int cc = c0 + j;
                int mm = m0;
                if (cc >= C) { cc -= C; mm = m1; }
                const float p = fminf(fmaxf(vv[j], EPS_CLIP), 1.f - EPS_CLIP);
                const bool t1 = (mm == cc);                 // target == 1
                const float parg = t1 ? p : (1.f - p);      // log argument
                const float qq   = t1 ? (1.f - p) : p;      // focal base
                const float w    = (t1 ? 0.25f : 0.75f) * qq * qq;
                const float l    = (mm == -2) ? 0.f : w * __log2f(parg);
                acc += l;
            }
        }
    }

    // ---------- Block reduction + atomics ----------
    float v0 = acc, v1 = reg_sum, v2 = pos_cnt;
    for (int off = 32; off; off >>= 1) {
        v0 += __shfl_down(v0, off);
        v1 += __shfl_down(v1, off);
        v2 += __shfl_down(v2, off);
    }
    const int wave = t >> 6;
    const int lane = t & 63;
    if (lane == 0) {
        s_red[0][wave] = v0;
        s_red[1][wave] = v1;
        s_red[2][wave] = v2;
    }
    __syncthreads();
    if (t == 0) {
        float a0 = 0.f, a1 = 0.f, a2 = 0.f;
        for (int w = 0; w < TPB / 64; ++w) {
            a0 += s_red[0][w];
            a1 += s_red[1][w];
            a2 += s_red[2][w];
        }
        atomicAdd(&accum[b],         a0 * (-LN2));  // undo log2 folding
        atomicAdd(&accum[B + b],     a1);
        atomicAdd(&accum[2 * B + b], a2);
    }
}

__global__ void focal_finalize_kernel(const float* __restrict__ ann,
                                      const float* __restrict__ accum,
                                      float* __restrict__ out)
{
    const int t = threadIdx.x;
    float cls_l = 0.f, reg_l = 0.f;
    if (t < B) {
        bool has = false;
        for (int m = 0; m < M; ++m)
            has = has || (ann[t * M * 5 + m * 5 + 4] != -1.0f);
        const float np = accum[2 * B + t];
        const float cs = accum[t];
        const float rs = accum[B + t];
        cls_l = has ? cs / fmaxf(np, 1.f) : 0.f;
        reg_l = (has && np > 0.f) ? rs / fmaxf(np * 4.f, 1.f) : 0.f;
    }
    for (int off = 4; off; off >>= 1) {
        cls_l += __shfl_down(cls_l, off);
        reg_l += __shfl_down(reg_l, off);
    }
    if (t == 0) {
        out[0] = cls_l * (1.f / B);
        out[1] = reg_l * (1.f / B);
    }
}

extern "C" void kernel_launch(void* const* d_in, const int* in_sizes, int n_in,
                              void* d_out, int out_size, void* d_ws, size_t ws_size,
                              hipStream_t stream) {
    const float* cls = (const float*)d_in[0];
    const float* reg = (const float*)d_in[1];
    const float* anc = (const float*)d_in[2];
    const float* ann = (const float*)d_in[3];
    float* out = (float*)d_out;
    float* accum = (float*)d_ws;

    hipMemsetAsync(accum, 0, 3 * B * sizeof(float), stream);

    dim3 grid((A + APB - 1) / APB, B);
    focal_fused_kernel<<<grid, TPB, 0, stream>>>(cls, reg, anc, ann, accum);
    focal_finalize_kernel<<<1, 64, 0, stream>>>(ann, accum, out);
}

// Round 3
// 67.562 us; speedup vs baseline: 1.5339x; 1.5339x over previous
//
#include <hip/hip_runtime.h>

constexpr int B = 8;
constexpr int A = 49104;
constexpr int C = 90;
constexpr int M = 32;
constexpr float EPS_CLIP = 1e-4f;
constexpr float LN2 = 0.6931471805599453f;

constexpr int APB = 256;  // anchors per block
constexpr int TPB = 256;  // threads per block
constexpr int UN  = 8;    // load batch depth (MLP)

// d_ws: [0..B) cls_sum(log2-domain), [B..2B) reg_sum, [2B..3B) pos_cnt

__global__ __launch_bounds__(TPB, 6) void focal_fused_kernel(
    const float* __restrict__ cls,   // [B, A, C]
    const float* __restrict__ reg,   // [B, A, 4]
    const float* __restrict__ anc,   // [A, 4]
    const float* __restrict__ ann,   // [B, M, 5]
    float* __restrict__ accum)       // [3*B]
{
    __shared__ float s_ann[M * 5];
    __shared__ int   s_meta[APB + 1];   // class idx if pos, -1 neg, -2 ignore
    __shared__ float s_red[3][TPB / 64];

    const int b     = blockIdx.y;
    const int abase = blockIdx.x * APB;
    const int t     = threadIdx.x;
    const int nA    = min(APB, A - abase);

    if (t < M * 5) s_ann[t] = ann[b * M * 5 + t];
    __syncthreads();

    float reg_sum = 0.f;
    float pos_cnt = 0.f;
    int   mymeta  = -1;

    // ---------- Phase 1: per-anchor GT assignment + regression loss ----------
    if (t < nA) {
        const int a = abase + t;
        const float4 ab = reinterpret_cast<const float4*>(anc)[a];
        const float aw = ab.z - ab.x;
        const float ah = ab.w - ab.y;
        const float areaA = aw * ah;

        float best = -INFINITY;
        int argm = 0;
        for (int m = 0; m < M; ++m) {
            const float bx1 = s_ann[m * 5 + 0];
            const float by1 = s_ann[m * 5 + 1];
            const float bx2 = s_ann[m * 5 + 2];
            const float by2 = s_ann[m * 5 + 3];
            const float lab = s_ann[m * 5 + 4];
            float iw = fminf(ab.z, bx2) - fmaxf(ab.x, bx1);
            float ih = fminf(ab.w, by2) - fmaxf(ab.y, by1);
            iw = fmaxf(iw, 0.f);
            ih = fmaxf(ih, 0.f);
            const float inter = iw * ih;
            const float ua = fmaxf(areaA + (bx2 - bx1) * (by2 - by1) - inter, 1e-8f);
            const float iou = inter / ua;
            const float val = (lab != -1.0f) ? iou : -1.0f;
            if (val > best) { best = val; argm = m; }  // strict > == first argmax
        }

        const bool pos = best >= 0.5f;
        const bool neg = best < 0.4f;
        mymeta = pos ? (int)s_ann[argm * 5 + 4] : (neg ? -1 : -2);

        if (pos) {
            pos_cnt = 1.f;
            const float gx1 = s_ann[argm * 5 + 0];
            const float gy1 = s_ann[argm * 5 + 1];
            const float gx2 = s_ann[argm * 5 + 2];
            const float gy2 = s_ann[argm * 5 + 3];
            const float acx = ab.x + 0.5f * aw;
            const float acy = ab.y + 0.5f * ah;
            const float gw0 = gx2 - gx1;
            const float gh0 = gy2 - gy1;
            const float gcx = gx1 + 0.5f * gw0;
            const float gcy = gy1 + 0.5f * gh0;
            const float gw = fmaxf(gw0, 1.f);
            const float gh = fmaxf(gh0, 1.f);
            const float4 rp = reinterpret_cast<const float4*>(reg)[(size_t)b * A + a];
            const float rt0 = (gcx - acx) / aw * 10.f;
            const float rt1 = (gcy - acy) / ah * 10.f;
            const float rt2 = __logf(gw / aw) * 5.f;
            const float rt3 = __logf(gh / ah) * 5.f;
            const float d0 = fabsf(rt0 - rp.x);
            const float d1 = fabsf(rt1 - rp.y);
            const float d2 = fabsf(rt2 - rp.z);
            const float d3 = fabsf(rt3 - rp.w);
            auto sl1 = [](float d) {
                return (d <= (1.f / 9.f)) ? 4.5f * d * d : d - (0.5f / 9.f);
            };
            reg_sum = sl1(d0) + sl1(d1) + sl1(d2) + sl1(d3);
        }
    }
    s_meta[t] = mymeta;                      // -1 for t >= nA (init value)
    if (t == 0) s_meta[APB] = -1;
    const int nspecial = __syncthreads_count(mymeta != -1);

    // ---------- Phase 2: stream classifications (8-deep load batches) ----------
    float acc = 0.f;
    const float4* cp = reinterpret_cast<const float4*>(
        cls + ((size_t)b * A + abase) * (size_t)C);
    const int n4 = (nA * C) >> 2;            // 5760 (full) / 4680 (last)

    if (nspecial == 0) {
        // FAST: all anchors plain negatives.  elem = 0.75*p^2*(-ln(1-p))
        // accumulate p^2*log2(1-p); scale by 0.75 then -ln2 later.
        for (int base = t; base < n4; base += UN * TPB) {
            float4 v[UN];
#pragma unroll
            for (int k = 0; k < UN; ++k) {
                const int ix = base + k * TPB;
                v[k] = cp[ix < n4 ? ix : 0];          // clamp: loads stay in-bounds
            }
#pragma unroll
            for (int k = 0; k < UN; ++k) {
                if (base + k * TPB < n4) {
                    const float vv[4] = {v[k].x, v[k].y, v[k].z, v[k].w};
#pragma unroll
                    for (int j = 0; j < 4; ++j) {
                        const float p = fminf(fmaxf(vv[j], EPS_CLIP), 1.f - EPS_CLIP);
                        acc = fmaf(p * p, __log2f(1.f - p), acc);
                    }
                }
            }
        }
        acc *= 0.75f;
    } else {
        // SLOW: block has positive/ignore anchors.
        for (int base = t; base < n4; base += UN * TPB) {
            float4 v[UN];
#pragma unroll
            for (int k = 0; k < UN; ++k) {
                const int ix = base + k * TPB;
                v[k] = cp[ix < n4 ? ix : 0];
            }
#pragma unroll
            for (int k = 0; k < UN; ++k) {
                const int ix = base + k * TPB;
                if (ix < n4) {
                    const int e  = ix << 2;
                    const int a0 = e / C;
                    const int c0 = e - a0 * C;
                    const int m0 = s_meta[a0];
                    const int m1 = (c0 >= C - 3) ? s_meta[a0 + 1] : m0;
                    const float vv[4] = {v[k].x, v[k].y, v[k].z, v[k].w};
#pragma unroll
                    for (int j = 0; j < 4; ++j) {
                        int cc = c0 + j;
                        int mm = m0;
                        if (cc >= C) { cc -= C; mm = m1; }
                        const float p = fminf(fmaxf(vv[j], EPS_CLIP), 1.f - EPS_CLIP);
                        const bool t1 = (mm == cc);
                        const float parg = t1 ? p : (1.f - p);
                        const float qq   = t1 ? (1.f - p) : p;
                        const float w    = (t1 ? 0.25f : 0.75f) * qq * qq;
                        acc += (mm == -2) ? 0.f : w * __log2f(parg);
                    }
                }
            }
        }
    }

    // ---------- Block reduction + atomics ----------
    float v0 = acc, v1 = reg_sum, v2 = pos_cnt;
    for (int off = 32; off; off >>= 1) {
        v0 += __shfl_down(v0, off);
        v1 += __shfl_down(v1, off);
        v2 += __shfl_down(v2, off);
    }
    const int wave = t >> 6;
    const int lane = t & 63;
    if (lane == 0) {
        s_red[0][wave] = v0;
        s_red[1][wave] = v1;
        s_red[2][wave] = v2;
    }
    __syncthreads();
    if (t == 0) {
        float a0 = 0.f, a1 = 0.f, a2 = 0.f;
        for (int w = 0; w < TPB / 64; ++w) {
            a0 += s_red[0][w];
            a1 += s_red[1][w];
            a2 += s_red[2][w];
        }
        atomicAdd(&accum[b],         a0 * (-LN2));  // undo log2 folding
        atomicAdd(&accum[B + b],     a1);
        atomicAdd(&accum[2 * B + b], a2);
    }
}

__global__ void focal_finalize_kernel(const float* __restrict__ ann,
                                      const float* __restrict__ accum,
                                      float* __restrict__ out)
{
    const int t = threadIdx.x;
    float cls_l = 0.f, reg_l = 0.f;
    if (t < B) {
        bool has = false;
        for (int m = 0; m < M; ++m)
            has = has || (ann[t * M * 5 + m * 5 + 4] != -1.0f);
        const float np = accum[2 * B + t];
        const float cs = accum[t];
        const float rs = accum[B + t];
        cls_l = has ? cs / fmaxf(np, 1.f) : 0.f;
        reg_l = (has && np > 0.f) ? rs / fmaxf(np * 4.f, 1.f) : 0.f;
    }
    for (int off = 4; off; off >>= 1) {
        cls_l += __shfl_down(cls_l, off);
        reg_l += __shfl_down(reg_l, off);
    }
    if (t == 0) {
        out[0] = cls_l * (1.f / B);
        out[1] = reg_l * (1.f / B);
    }
}

extern "C" void kernel_launch(void* const* d_in, const int* in_sizes, int n_in,
                              void* d_out, int out_size, void* d_ws, size_t ws_size,
                              hipStream_t stream) {
    const float* cls = (const float*)d_in[0];
    const float* reg = (const float*)d_in[1];
    const float* anc = (const float*)d_in[2];
    const float* ann = (const float*)d_in[3];
    float* out = (float*)d_out;
    float* accum = (float*)d_ws;

    hipMemsetAsync(accum, 0, 3 * B * sizeof(float), stream);

    dim3 grid((A + APB - 1) / APB, B);
    focal_fused_kernel<<<grid, TPB, 0, stream>>>(cls, reg, anc, ann, accum);
    focal_finalize_kernel<<<1, 64, 0, stream>>>(ann, accum, out);
}